// Round 1
// baseline (404.638 us; speedup 1.0000x reference)
//
#include <hip/hip_runtime.h>

typedef __attribute__((ext_vector_type(8))) short bf16x8;   // 8 bf16 (4 VGPRs)
typedef __attribute__((ext_vector_type(4))) float f32x4;    // MFMA acc
typedef unsigned short u16;
typedef unsigned int   u32;

#define DEVI __device__ __forceinline__

// fp32 -> bf16 round-to-nearest-even
DEVI u16 f2bf(float f) {
    u32 u = __float_as_uint(f);
    u32 r = (u + 0x7FFFu + ((u >> 16) & 1u)) >> 16;
    return (u16)r;
}
DEVI u32 pk(float a, float b) {
    return (u32)f2bf(a) | ((u32)f2bf(b) << 16);
}

// ---------------------------------------------------------------------------
// Kernel 1: d[i] = rsqrt(rowsum(adj)); optionally write bf16 copy of adj.
// ---------------------------------------------------------------------------
template<bool WRITE_H>
__global__ __launch_bounds__(256)
void deg_k(const float* __restrict__ adj, float* __restrict__ dvec,
           u16* __restrict__ adjh) {
    const int row = blockIdx.x;
    const int t   = threadIdx.x;
    const float4* p = (const float4*)(adj + (long long)row * 8192);
    float s = 0.f;
#pragma unroll
    for (int i = 0; i < 8; ++i) {
        float4 v = p[t + i * 256];
        s += (v.x + v.y) + (v.z + v.w);
        if constexpr (WRITE_H) {
            *(uint2*)(adjh + (long long)row * 8192 + (t + i * 256) * 4) =
                make_uint2(pk(v.x, v.y), pk(v.z, v.w));
        }
    }
#pragma unroll
    for (int off = 32; off; off >>= 1) s += __shfl_down(s, off, 64);
    __shared__ float red[4];
    if ((t & 63) == 0) red[t >> 6] = s;
    __syncthreads();
    if (t == 0) dvec[row] = 1.0f / sqrtf(red[0] + red[1] + red[2] + red[3]);
}

// ---------------------------------------------------------------------------
// Generic MFMA GEMM:  Out(MxN) = A(MxK) * B(NxK)^T   (B stored [N][K])
//   A: fp32 (cvt on the fly) or bf16.  B: fp32 or bf16.
//   EPI 0: f32 partials  Out[kp*kstride + m*ldo + n] = acc
//   EPI 1: bf16          Out[m*ldo + n] = bf16(acc * d[n])
//   EPI 2: bf16          Out[m*ldo + n] = bf16(relu(acc * d[m]))
// 256 threads, BK=64, single-buffer LDS, XOR-swizzled (T2), issue-early (T14).
// ---------------------------------------------------------------------------
template<int BM, int BN, int WM, int WN, bool AF32, bool BF32, int EPI>
__global__ __launch_bounds__(256)
void gemm_k(const void* __restrict__ Ap, int lda,
            const void* __restrict__ Bp, int ldb,
            void* __restrict__ Op, int ldo,
            const float* __restrict__ dvec,
            int mtiles, int ntiles, int klen, long long kstride) {
    constexpr int BK  = 64;
    constexpr int WTM = BM / WM, WTN = BN / WN;
    constexpr int FM  = WTM / 16, FN = WTN / 16;
    constexpr int SA  = BM * BK;   // u16 elements
    constexpr int SB  = BN * BK;
    __shared__ __align__(16) u16 lds[SA + SB];

    const int t   = threadIdx.x;
    const int bid = blockIdx.x;
    const int mt  = bid % mtiles;
    const int nt  = (bid / mtiles) % ntiles;
    const int kp  = bid / (mtiles * ntiles);
    const int m0  = mt * BM, n0 = nt * BN;
    const long long k00 = (long long)kp * klen;

    const float* Af = (const float*)Ap;
    const u16*   Ah = (const u16*)Ap;
    const float* Bf = (const float*)Bp;
    const u16*   Bh = (const u16*)Bp;

    constexpr int NA = AF32 ? (BM * 16 / 256) : ((BM * 8 + 255) / 256);
    constexpr int NB = BF32 ? (BN * 16 / 256) : ((BN * 8 + 255) / 256);
    float4 raf[AF32 ? NA : 1];  uint4 rah[AF32 ? 1 : NA];
    float4 rbf[BF32 ? NB : 1];  uint4 rbh[BF32 ? 1 : NB];

    f32x4 acc[FM][FN] = {};

    const int lane = t & 63;
    const int lrow = lane & 15, kg = lane >> 4;
    const int wave = t >> 6;
    const int wr0  = (wave % WM) * WTM;
    const int wc0  = (wave / WM) * WTN;

    auto issue = [&](long long k0) {
        if constexpr (AF32) {
#pragma unroll
            for (int i = 0; i < NA; ++i) {
                int idx = t + i * 256, r = idx >> 4, c = idx & 15;
                raf[i] = *(const float4*)(Af + (long long)(m0 + r) * lda + k0 + c * 4);
            }
        } else {
#pragma unroll
            for (int i = 0; i < NA; ++i) {
                int idx = t + i * 256;
                if (BM * 8 < 256 && idx >= BM * 8) break;
                int r = idx >> 3, j = idx & 7;
                rah[i] = *(const uint4*)(Ah + (long long)(m0 + r) * lda + k0 + j * 8);
            }
        }
        if constexpr (BF32) {
#pragma unroll
            for (int i = 0; i < NB; ++i) {
                int idx = t + i * 256, r = idx >> 4, c = idx & 15;
                rbf[i] = *(const float4*)(Bf + (long long)(n0 + r) * ldb + k0 + c * 4);
            }
        } else {
#pragma unroll
            for (int i = 0; i < NB; ++i) {
                int idx = t + i * 256;
                if (BN * 8 < 256 && idx >= BN * 8) break;
                int r = idx >> 3, j = idx & 7;
                rbh[i] = *(const uint4*)(Bh + (long long)(n0 + r) * ldb + k0 + j * 8);
            }
        }
    };

    auto stash = [&]() {
        char* AB = (char*)lds;
        char* BB = (char*)(lds + SA);
        if constexpr (AF32) {
#pragma unroll
            for (int i = 0; i < NA; ++i) {
                int idx = t + i * 256, r = idx >> 4, c = idx & 15;
                int off = r * 128 + ((((c >> 1) ^ (r & 7)) << 4) | ((c & 1) << 3));
                *(uint2*)(AB + off) =
                    make_uint2(pk(raf[i].x, raf[i].y), pk(raf[i].z, raf[i].w));
            }
        } else {
#pragma unroll
            for (int i = 0; i < NA; ++i) {
                int idx = t + i * 256;
                if (BM * 8 < 256 && idx >= BM * 8) break;
                int r = idx >> 3, j = idx & 7;
                *(uint4*)(AB + r * 128 + ((j ^ (r & 7)) << 4)) = rah[i];
            }
        }
        if constexpr (BF32) {
#pragma unroll
            for (int i = 0; i < NB; ++i) {
                int idx = t + i * 256, r = idx >> 4, c = idx & 15;
                int off = r * 128 + ((((c >> 1) ^ (r & 7)) << 4) | ((c & 1) << 3));
                *(uint2*)(BB + off) =
                    make_uint2(pk(rbf[i].x, rbf[i].y), pk(rbf[i].z, rbf[i].w));
            }
        } else {
#pragma unroll
            for (int i = 0; i < NB; ++i) {
                int idx = t + i * 256;
                if (BN * 8 < 256 && idx >= BN * 8) break;
                int r = idx >> 3, j = idx & 7;
                *(uint4*)(BB + r * 128 + ((j ^ (r & 7)) << 4)) = rbh[i];
            }
        }
    };

    auto compute = [&]() {
        const char* AB = (const char*)lds;
        const char* BB = (const char*)(lds + SA);
#pragma unroll
        for (int s = 0; s < 2; ++s) {
            bf16x8 a[FM]; bf16x8 b[FN];
#pragma unroll
            for (int f = 0; f < FM; ++f) {
                int r = wr0 + f * 16 + lrow;
                a[f] = *(const bf16x8*)(AB + r * 128 + (((s * 4 + kg) ^ (r & 7)) << 4));
            }
#pragma unroll
            for (int f = 0; f < FN; ++f) {
                int r = wc0 + f * 16 + lrow;
                b[f] = *(const bf16x8*)(BB + r * 128 + (((s * 4 + kg) ^ (r & 7)) << 4));
            }
#pragma unroll
            for (int i = 0; i < FM; ++i)
#pragma unroll
                for (int j = 0; j < FN; ++j)
                    acc[i][j] = __builtin_amdgcn_mfma_f32_16x16x32_bf16(
                        a[i], b[j], acc[i][j], 0, 0, 0);
        }
    };

    issue(k00);
    stash();
    __syncthreads();
    const int NT = klen / BK;
    for (int tt = 0; tt < NT; ++tt) {
        bool more = (tt + 1 < NT);
        if (more) issue(k00 + (long long)(tt + 1) * BK);  // T14: issue early
        compute();
        __syncthreads();
        if (more) { stash(); __syncthreads(); }
    }

    // epilogue: C/D layout col = lane&15, row = (lane>>4)*4 + reg  [m89]
#pragma unroll
    for (int i = 0; i < FM; ++i)
#pragma unroll
        for (int j = 0; j < FN; ++j)
#pragma unroll
            for (int r = 0; r < 4; ++r) {
                int m = m0 + wr0 + i * 16 + kg * 4 + r;
                int n = n0 + wc0 + j * 16 + lrow;
                float v = acc[i][j][r];
                if constexpr (EPI == 0) {
                    ((float*)Op)[kp * kstride + (long long)m * ldo + n] = v;
                } else if constexpr (EPI == 1) {
                    ((u16*)Op)[(long long)m * ldo + n] = f2bf(v * dvec[n]);
                } else {
                    ((u16*)Op)[(long long)m * ldo + n] =
                        f2bf(fmaxf(v * dvec[m], 0.0f));
                }
            }
}

// ---------------------------------------------------------------------------
// x1[j][h] = bf16(relu(d[j] * sum_p H1p[p][j][h]))
// ---------------------------------------------------------------------------
__global__ __launch_bounds__(256)
void reduce1_k(const float* __restrict__ H, const float* __restrict__ dvec,
               u16* __restrict__ x1, int parts) {
    long long i = ((long long)blockIdx.x * 256 + threadIdx.x) * 4;
    float4 s = *(const float4*)(H + i);
    for (int p = 1; p < parts; ++p) {
        float4 v = *(const float4*)(H + (long long)p * 2097152 + i);
        s.x += v.x; s.y += v.y; s.z += v.z; s.w += v.w;
    }
    float dv = dvec[i >> 8];
    *(uint2*)(x1 + i) = make_uint2(
        pk(fmaxf(s.x * dv, 0.f), fmaxf(s.y * dv, 0.f)),
        pk(fmaxf(s.z * dv, 0.f), fmaxf(s.w * dv, 0.f)));
}

// ---------------------------------------------------------------------------
// out[i][c] = log_softmax(d[i] * sum_p H2p[p][i][c])
// ---------------------------------------------------------------------------
__global__ __launch_bounds__(256)
void final_k(const float* __restrict__ H, const float* __restrict__ dvec,
             float* __restrict__ out, int parts) {
    int i = blockIdx.x * 256 + threadIdx.x;
    float z[16];
#pragma unroll
    for (int c = 0; c < 16; c += 4) {
        float4 v = *(const float4*)(H + (long long)i * 16 + c);
        z[c] = v.x; z[c + 1] = v.y; z[c + 2] = v.z; z[c + 3] = v.w;
    }
    for (int p = 1; p < parts; ++p) {
#pragma unroll
        for (int c = 0; c < 16; c += 4) {
            float4 v = *(const float4*)(H + (long long)p * 131072 +
                                        (long long)i * 16 + c);
            z[c] += v.x; z[c + 1] += v.y; z[c + 2] += v.z; z[c + 3] += v.w;
        }
    }
    float dv = dvec[i];
    float m = -1e30f;
#pragma unroll
    for (int c = 0; c < 16; ++c) { z[c] *= dv; m = fmaxf(m, z[c]); }
    float l = 0.f;
#pragma unroll
    for (int c = 0; c < 16; ++c) l += __expf(z[c] - m);
    float lse = m + __logf(l);
#pragma unroll
    for (int c = 0; c < 16; c += 4) {
        float4 v;
        v.x = z[c] - lse; v.y = z[c + 1] - lse;
        v.z = z[c + 2] - lse; v.w = z[c + 3] - lse;
        *(float4*)(out + (long long)i * 16 + c) = v;
    }
}

// ---------------------------------------------------------------------------
extern "C" void kernel_launch(void* const* d_in, const int* in_sizes, int n_in,
                              void* d_out, int out_size, void* d_ws, size_t ws_size,
                              hipStream_t stream) {
    (void)in_sizes; (void)n_in; (void)out_size;
    const float* X   = (const float*)d_in[0];   // [8192,512]
    const float* ADJ = (const float*)d_in[1];   // [8192,8192]
    const float* W1  = (const float*)d_in[2];   // [256,512]
    const float* W2  = (const float*)d_in[3];   // [16,256]
    float* out = (float*)d_out;
    char*  ws  = (char*)d_ws;

    float* dvec = (float*)(ws + 0);              //  32 KB
    u16*   B1   = (u16*)(ws + 32768);            //   4 MB  [256 h][8192 j]
    u16*   X1   = (u16*)(ws + 4227072);          //   4 MB  [8192 j][256 h]
    u16*   B2   = (u16*)(ws + 8421376);          // 256 KB  [16 c][8192 j]
    float* H2P  = (float*)(ws + 8683520);        // <=4 MB  [SK2][8192][16]
    float* H1P  = (float*)(ws + 12877824);       // <=32 MB [SK1][8192][256]
    u16*   ADJH = (u16*)(ws + 46432256);         // 128 MB  bf16 adjacency

    int SK1, SK2; bool fastA, useH1P;
    if      (ws_size >= 180649984ULL) { fastA = true;  SK1 = 4; SK2 = 8; useH1P = true;  }
    else if (ws_size >= 46432256ULL)  { fastA = false; SK1 = 4; SK2 = 8; useH1P = true;  }
    else if (ws_size >= 29655040ULL)  { fastA = false; SK1 = 2; SK2 = 8; useH1P = true;  }
    else if (ws_size >= 12877824ULL)  { fastA = false; SK1 = 1; SK2 = 8; useH1P = false; }
    else                              { fastA = false; SK1 = 1; SK2 = 1; useH1P = false; }

    // 1) degrees (+ optional bf16 adjacency copy)
    if (fastA) deg_k<true ><<<8192, 256, 0, stream>>>(ADJ, dvec, ADJH);
    else       deg_k<false><<<8192, 256, 0, stream>>>(ADJ, dvec, nullptr);

    // 2) B1[h][j] = bf16(d_j * (X @ W1^T)[j,h]) : A=W1[256,512], B=X[8192,512]
    gemm_k<64, 256, 1, 4, true, true, 1><<<4 * 32, 256, 0, stream>>>(
        W1, 512, X, 512, B1, 8192, dvec, 4, 32, 512, 0);

    // 3) layer-1 aggregate: H1 = A @ B1^T  (M=8192, N=256, K=8192)
    if (useH1P) {
        if (fastA)
            gemm_k<64, 256, 1, 4, false, false, 0><<<128 * SK1, 256, 0, stream>>>(
                ADJH, 8192, B1, 8192, H1P, 256, dvec, 128, 1, 8192 / SK1, 2097152LL);
        else
            gemm_k<64, 256, 1, 4, true, false, 0><<<128 * SK1, 256, 0, stream>>>(
                ADJ, 8192, B1, 8192, H1P, 256, dvec, 128, 1, 8192 / SK1, 2097152LL);
        reduce1_k<<<2048, 256, 0, stream>>>(H1P, dvec, X1, SK1);
    } else {
        gemm_k<64, 256, 1, 4, true, false, 2><<<128, 256, 0, stream>>>(
            ADJ, 8192, B1, 8192, X1, 256, dvec, 128, 1, 8192, 0);
    }

    // 4) B2[c][j] = bf16(d_j * (X1 @ W2^T)[j,c]) : A=W2[16,256], B=X1[8192,256]
    gemm_k<16, 256, 1, 4, true, false, 1><<<1 * 32, 256, 0, stream>>>(
        W2, 256, X1, 256, B2, 8192, dvec, 1, 32, 256, 0);

    // 5) layer-2 aggregate: H2 = A @ B2^T  (M=8192, N=16, K=8192)
    if (fastA)
        gemm_k<128, 16, 4, 1, false, false, 0><<<64 * SK2, 256, 0, stream>>>(
            ADJH, 8192, B2, 8192, H2P, 16, dvec, 64, 1, 8192 / SK2, 131072LL);
    else
        gemm_k<128, 16, 4, 1, true, false, 0><<<64 * SK2, 256, 0, stream>>>(
            ADJ, 8192, B2, 8192, H2P, 16, dvec, 64, 1, 8192 / SK2, 131072LL);

    // 6) d_i scale + log-softmax
    final_k<<<32, 256, 0, stream>>>(H2P, dvec, out, SK2);
}

// Round 2
// 250.105 us; speedup vs baseline: 1.6179x; 1.6179x over previous
//
#include <hip/hip_runtime.h>

typedef __attribute__((ext_vector_type(8))) short bf16x8;   // 8 bf16 (4 VGPRs)
typedef __attribute__((ext_vector_type(4))) float f32x4;    // MFMA acc
typedef unsigned short u16;
typedef unsigned int   u32;

#define DEVI __device__ __forceinline__

// fp32 -> bf16 round-to-nearest-even
DEVI u16 f2bf(float f) {
    u32 u = __float_as_uint(f);
    u32 r = (u + 0x7FFFu + ((u >> 16) & 1u)) >> 16;
    return (u16)r;
}
DEVI u32 pk(float a, float b) {
    return (u32)f2bf(a) | ((u32)f2bf(b) << 16);
}

// async global->LDS, 16B per lane (global_load_lds_dwordx4)
DEVI void gld16(const u16* g, u16* l) {
    __builtin_amdgcn_global_load_lds(
        (const __attribute__((address_space(1))) u32*)g,
        (__attribute__((address_space(3))) u32*)l, 16, 0, 0);
}

// ---------------------------------------------------------------------------
// Kernel 1: d[i] = rsqrt(rowsum(adj)); optionally write bf16 PRE-SWIZZLED adj.
// Swizzle: 16B chunk index c within each 64-elem k-group stored at c^(row&7),
// matching agg_k's LDS ds_read XOR (rule #21: producer-side swizzle).
// ---------------------------------------------------------------------------
template<bool WRITE_H>
__global__ __launch_bounds__(256)
void deg_k(const float* __restrict__ adj, float* __restrict__ dvec,
           u16* __restrict__ adjh) {
    const int row = blockIdx.x;
    const int t   = threadIdx.x;
    const float4* p = (const float4*)(adj + (long long)row * 8192);
    float s = 0.f;
#pragma unroll
    for (int i = 0; i < 4; ++i) {
        int c = t + i * 256;                 // 16B-chunk index in [0,1024)
        float4 v0 = p[2 * c];
        float4 v1 = p[2 * c + 1];
        s += (v0.x + v0.y) + (v0.z + v0.w) + (v1.x + v1.y) + (v1.z + v1.w);
        if constexpr (WRITE_H) {
            uint4 h = make_uint4(pk(v0.x, v0.y), pk(v0.z, v0.w),
                                 pk(v1.x, v1.y), pk(v1.z, v1.w));
            int cs = (c & ~7) | ((c & 7) ^ (row & 7));
            *(uint4*)(adjh + (long long)row * 8192 + (long long)cs * 8) = h;
        }
    }
#pragma unroll
    for (int off = 32; off; off >>= 1) s += __shfl_down(s, off, 64);
    __shared__ float red[4];
    if ((t & 63) == 0) red[t >> 6] = s;
    __syncthreads();
    if (t == 0) dvec[row] = 1.0f / sqrtf(red[0] + red[1] + red[2] + red[3]);
}

// ---------------------------------------------------------------------------
// Small MFMA GEMM (fp32 inputs, converted in-flight):  Out = A(MxK) * B(NxK)^T
//   EPI 0: f32 partials   EPI 1: bf16 * d[n]   EPI 2: bf16 relu(*d[m])
//   EPI 3: bf16 * d[n], column-swizzled store (producer-side T2 swizzle)
// No reg-staging across phases (avoids the R1 scratch-spill disaster).
// ---------------------------------------------------------------------------
template<int BM, int BN, int WM, int WN, bool AF32, bool BF32, int EPI>
__global__ __launch_bounds__(256)
void gemm_k(const void* __restrict__ Ap, int lda,
            const void* __restrict__ Bp, int ldb,
            void* __restrict__ Op, int ldo,
            const float* __restrict__ dvec,
            int mtiles, int ntiles, int klen, long long kstride) {
    constexpr int BK  = 64;
    constexpr int WTM = BM / WM, WTN = BN / WN;
    constexpr int FM  = WTM / 16, FN = WTN / 16;
    constexpr int SA  = BM * BK;   // u16 elements
    constexpr int SB  = BN * BK;
    __shared__ __align__(16) u16 lds[SA + SB];

    const int t   = threadIdx.x;
    const int bid = blockIdx.x;
    const int mt  = bid % mtiles;
    const int nt  = (bid / mtiles) % ntiles;
    const int kp  = bid / (mtiles * ntiles);
    const int m0  = mt * BM, n0 = nt * BN;
    const long long k00 = (long long)kp * klen;

    const float* Af = (const float*)Ap;
    const u16*   Ah = (const u16*)Ap;
    const float* Bf = (const float*)Bp;
    const u16*   Bh = (const u16*)Bp;

    f32x4 acc[FM][FN] = {};

    const int lane = t & 63;
    const int lrow = lane & 15, kg = lane >> 4;
    const int wave = t >> 6;
    const int wr0  = (wave % WM) * WTM;
    const int wc0  = (wave / WM) * WTN;

    auto stage = [&](long long k0) {
        char* AB = (char*)lds;
        char* BB = (char*)(lds + SA);
        if constexpr (AF32) {
            constexpr int NA = BM * 16 / 256;
#pragma unroll
            for (int i = 0; i < NA; ++i) {
                int idx = t + i * 256, r = idx >> 4, c = idx & 15;
                float4 v = *(const float4*)(Af + (long long)(m0 + r) * lda + k0 + c * 4);
                int off = r * 128 + ((((c >> 1) ^ (r & 7)) << 4) | ((c & 1) << 3));
                *(uint2*)(AB + off) = make_uint2(pk(v.x, v.y), pk(v.z, v.w));
            }
        } else {
            constexpr int NA = (BM * 8 + 255) / 256;
#pragma unroll
            for (int i = 0; i < NA; ++i) {
                int idx = t + i * 256;
                if (BM * 8 >= 256 || idx < BM * 8) {
                    int r = idx >> 3, j = idx & 7;
                    uint4 v = *(const uint4*)(Ah + (long long)(m0 + r) * lda + k0 + j * 8);
                    *(uint4*)(AB + r * 128 + ((j ^ (r & 7)) << 4)) = v;
                }
            }
        }
        if constexpr (BF32) {
            constexpr int NB = BN * 16 / 256;
#pragma unroll
            for (int i = 0; i < NB; ++i) {
                int idx = t + i * 256, r = idx >> 4, c = idx & 15;
                float4 v = *(const float4*)(Bf + (long long)(n0 + r) * ldb + k0 + c * 4);
                int off = r * 128 + ((((c >> 1) ^ (r & 7)) << 4) | ((c & 1) << 3));
                *(uint2*)(BB + off) = make_uint2(pk(v.x, v.y), pk(v.z, v.w));
            }
        } else {
            constexpr int NB = (BN * 8 + 255) / 256;
#pragma unroll
            for (int i = 0; i < NB; ++i) {
                int idx = t + i * 256;
                if (BN * 8 >= 256 || idx < BN * 8) {
                    int r = idx >> 3, j = idx & 7;
                    uint4 v = *(const uint4*)(Bh + (long long)(n0 + r) * ldb + k0 + j * 8);
                    *(uint4*)(BB + r * 128 + ((j ^ (r & 7)) << 4)) = v;
                }
            }
        }
    };

    auto compute = [&]() {
        const char* AB = (const char*)lds;
        const char* BB = (const char*)(lds + SA);
#pragma unroll
        for (int s = 0; s < 2; ++s) {
            bf16x8 a[FM]; bf16x8 b[FN];
#pragma unroll
            for (int f = 0; f < FM; ++f) {
                int r = wr0 + f * 16 + lrow;
                a[f] = *(const bf16x8*)(AB + r * 128 + (((s * 4 + kg) ^ (r & 7)) << 4));
            }
#pragma unroll
            for (int f = 0; f < FN; ++f) {
                int r = wc0 + f * 16 + lrow;
                b[f] = *(const bf16x8*)(BB + r * 128 + (((s * 4 + kg) ^ (r & 7)) << 4));
            }
#pragma unroll
            for (int i = 0; i < FM; ++i)
#pragma unroll
                for (int j = 0; j < FN; ++j)
                    acc[i][j] = __builtin_amdgcn_mfma_f32_16x16x32_bf16(
                        a[i], b[j], acc[i][j], 0, 0, 0);
        }
    };

    const int NT = klen / BK;
    for (int tt = 0; tt < NT; ++tt) {
        stage(k00 + (long long)tt * BK);
        __syncthreads();
        compute();
        __syncthreads();
    }

    // epilogue: C/D layout col = lane&15, row = (lane>>4)*4 + reg  [m89]
#pragma unroll
    for (int i = 0; i < FM; ++i)
#pragma unroll
        for (int j = 0; j < FN; ++j)
#pragma unroll
            for (int r = 0; r < 4; ++r) {
                int m = m0 + wr0 + i * 16 + kg * 4 + r;
                int n = n0 + wc0 + j * 16 + lrow;
                float v = acc[i][j][r];
                if constexpr (EPI == 0) {
                    ((float*)Op)[kp * kstride + (long long)m * ldo + n] = v;
                } else if constexpr (EPI == 1) {
                    ((u16*)Op)[(long long)m * ldo + n] = f2bf(v * dvec[n]);
                } else if constexpr (EPI == 2) {
                    ((u16*)Op)[(long long)m * ldo + n] =
                        f2bf(fmaxf(v * dvec[m], 0.0f));
                } else {  // EPI==3: swizzled bf16 store (consumer = agg_k)
                    int ns = (n & ~63) | ((((n >> 3) & 7) ^ (m & 7)) << 3) | (n & 7);
                    ((u16*)Op)[(long long)m * ldo + ns] = f2bf(v * dvec[n]);
                }
            }
}

// ---------------------------------------------------------------------------
// Aggregate MFMA GEMM (m97-style): Out(MxN,f32 partials) = A(MxK) * B(NxK)^T
// A,B bf16, PRE-SWIZZLED in global. global_load_lds width=16, double-buffered
// LDS, counted vmcnt (T4), raw s_barrier. ntiles fixed = 1 (A read once).
//   BM rows of A, BNS staged B rows (padded), BNC computed B rows.
// ---------------------------------------------------------------------------
template<int BM, int BNS, int BNC, int WM, int WN>
__global__ __launch_bounds__(256)
void agg_k(const u16* __restrict__ A, int lda,
           const u16* __restrict__ B, int ldb,
           float* __restrict__ Op, int ldo,
           int mtiles, int klen, long long kstride) {
    constexpr int BK  = 64;
    constexpr int CH  = (BM + BNS) * 8;      // 16B chunks per tile
    constexpr int NLD = CH / 256;            // gload_lds per thread per K-step
    constexpr int WTM = BM / WM, WTN = BNC / WN;
    constexpr int FM  = WTM / 16, FN = WTN / 16;
    constexpr int BUF = (BM + BNS) * BK;     // u16 per buffer
    __shared__ __align__(16) u16 lds[2 * BUF];

    const int t   = threadIdx.x;
    const int bid = blockIdx.x;
    const int mt  = bid % mtiles;
    const int kp  = bid / mtiles;
    const int m0  = mt * BM;
    const long long k00 = (long long)kp * klen;

    const int lane = t & 63, lrow = lane & 15, kg = lane >> 4;
    const int wave = t >> 6;
    const int wr0  = (wave % WM) * WTM;
    const int wc0  = (wave / WM) * WTN;

    f32x4 acc[FM][FN] = {};

    auto stage = [&](long long k0, int pb) {
        u16* dst = lds + pb * BUF;
#pragma unroll
        for (int i = 0; i < NLD; ++i) {
            int c = t + i * 256;
            const u16* src;
            if (i * 256 < BM * 8) {          // compile-time region split
                src = A + (long long)(m0 + (c >> 3)) * lda + k0 + (c & 7) * 8;
            } else {
                int cb = c - BM * 8;
                src = B + (long long)(cb >> 3) * ldb + k0 + (cb & 7) * 8;
            }
            gld16(src, dst + (long long)c * 8);
        }
    };

    auto compute = [&](int pb) {
        const char* base = (const char*)(lds + pb * BUF);
        const char* Bb   = base + BM * 128;
#pragma unroll
        for (int s = 0; s < 2; ++s) {
            bf16x8 a[FM]; bf16x8 b[FN];
#pragma unroll
            for (int f = 0; f < FM; ++f) {
                int r = wr0 + f * 16 + lrow;
                a[f] = *(const bf16x8*)(base + r * 128 + (((s * 4 + kg) ^ (r & 7)) << 4));
            }
#pragma unroll
            for (int f = 0; f < FN; ++f) {
                int r = wc0 + f * 16 + lrow;
                b[f] = *(const bf16x8*)(Bb + r * 128 + (((s * 4 + kg) ^ (r & 7)) << 4));
            }
#pragma unroll
            for (int i = 0; i < FM; ++i)
#pragma unroll
                for (int j = 0; j < FN; ++j)
                    acc[i][j] = __builtin_amdgcn_mfma_f32_16x16x32_bf16(
                        a[i], b[j], acc[i][j], 0, 0, 0);
        }
    };

    stage(k00, 0);
    const int NT = klen / BK;
    for (int tt = 0; tt < NT; ++tt) {
        const int p = tt & 1;
        if (tt + 1 < NT) {
            stage(k00 + (long long)(tt + 1) * BK, p ^ 1);
            // wait for THIS K-step's loads only; next tile's stay in flight (T4)
            if constexpr (NLD == 10)
                asm volatile("s_waitcnt vmcnt(10)" ::: "memory");
            else if constexpr (NLD == 5)
                asm volatile("s_waitcnt vmcnt(5)" ::: "memory");
            else
                asm volatile("s_waitcnt vmcnt(0)" ::: "memory");
        } else {
            asm volatile("s_waitcnt vmcnt(0)" ::: "memory");
        }
        __builtin_amdgcn_s_barrier();        // raw: no implicit vmcnt(0) drain
        compute(p);
        asm volatile("" ::: "memory");
        __builtin_amdgcn_s_barrier();        // all reads of buf p done
    }

#pragma unroll
    for (int i = 0; i < FM; ++i)
#pragma unroll
        for (int j = 0; j < FN; ++j)
#pragma unroll
            for (int r = 0; r < 4; ++r) {
                int m = m0 + wr0 + i * 16 + kg * 4 + r;
                int n = wc0 + j * 16 + lrow;
                Op[kp * kstride + (long long)m * ldo + n] = acc[i][j][r];
            }
}

// ---------------------------------------------------------------------------
// x1[j][h] = bf16(relu(d[j] * sum_p H1p[p][j][h]))
// ---------------------------------------------------------------------------
__global__ __launch_bounds__(256)
void reduce1_k(const float* __restrict__ H, const float* __restrict__ dvec,
               u16* __restrict__ x1, int parts) {
    long long i = ((long long)blockIdx.x * 256 + threadIdx.x) * 4;
    float4 s = *(const float4*)(H + i);
    for (int p = 1; p < parts; ++p) {
        float4 v = *(const float4*)(H + (long long)p * 2097152 + i);
        s.x += v.x; s.y += v.y; s.z += v.z; s.w += v.w;
    }
    float dv = dvec[i >> 8];
    *(uint2*)(x1 + i) = make_uint2(
        pk(fmaxf(s.x * dv, 0.f), fmaxf(s.y * dv, 0.f)),
        pk(fmaxf(s.z * dv, 0.f), fmaxf(s.w * dv, 0.f)));
}

// ---------------------------------------------------------------------------
// out[i][c] = log_softmax(d[i] * sum_p H2p[p][i][c])
// ---------------------------------------------------------------------------
__global__ __launch_bounds__(256)
void final_k(const float* __restrict__ H, const float* __restrict__ dvec,
             float* __restrict__ out, int parts) {
    int i = blockIdx.x * 256 + threadIdx.x;
    float z[16];
#pragma unroll
    for (int c = 0; c < 16; c += 4) {
        float4 v = *(const float4*)(H + (long long)i * 16 + c);
        z[c] = v.x; z[c + 1] = v.y; z[c + 2] = v.z; z[c + 3] = v.w;
    }
    for (int p = 1; p < parts; ++p) {
#pragma unroll
        for (int c = 0; c < 16; c += 4) {
            float4 v = *(const float4*)(H + (long long)p * 131072 +
                                        (long long)i * 16 + c);
            z[c] += v.x; z[c + 1] += v.y; z[c + 2] += v.z; z[c + 3] += v.w;
        }
    }
    float dv = dvec[i];
    float m = -1e30f;
#pragma unroll
    for (int c = 0; c < 16; ++c) { z[c] *= dv; m = fmaxf(m, z[c]); }
    float l = 0.f;
#pragma unroll
    for (int c = 0; c < 16; ++c) l += __expf(z[c] - m);
    float lse = m + __logf(l);
#pragma unroll
    for (int c = 0; c < 16; c += 4) {
        float4 v;
        v.x = z[c] - lse; v.y = z[c + 1] - lse;
        v.z = z[c + 2] - lse; v.w = z[c + 3] - lse;
        *(float4*)(out + (long long)i * 16 + c) = v;
    }
}

// ---------------------------------------------------------------------------
extern "C" void kernel_launch(void* const* d_in, const int* in_sizes, int n_in,
                              void* d_out, int out_size, void* d_ws, size_t ws_size,
                              hipStream_t stream) {
    (void)in_sizes; (void)n_in; (void)out_size;
    const float* X   = (const float*)d_in[0];   // [8192,512]
    const float* ADJ = (const float*)d_in[1];   // [8192,8192]
    const float* W1  = (const float*)d_in[2];   // [256,512]
    const float* W2  = (const float*)d_in[3];   // [16,256]
    float* out = (float*)d_out;
    char*  ws  = (char*)d_ws;

    if (ws_size >= 176193536ULL) {
        // ---- fast path: bf16 pre-swizzled adjacency + gload_lds aggregates
        float* dvec = (float*)(ws + 0);            //  32 KB
        u16*   B1   = (u16*)(ws + 32768);          //   4 MB [256 h][8192 j] swz
        u16*   X1   = (u16*)(ws + 4227072);        //   4 MB [8192 j][256 h]
        u16*   ADJH = (u16*)(ws + 8421376);        // 128 MB [8192][8192] swz
        float* H1P  = (float*)(ws + 142639104);    //  32 MB [4][8192][256]
        u16*   B2   = (u16*)(ws + 142639104);      // 512 KB (aliases dead H1P)
        float* H2P  = (float*)(ws + 143163392);    //   4 MB [8][8192][16]

        // 1) degrees + bf16 swizzled adjacency
        deg_k<true><<<8192, 256, 0, stream>>>(ADJ, dvec, ADJH);

        // 2) B1[h][j] = bf16(d_j * (X @ W1^T)[j,h]), swizzled store
        gemm_k<64, 256, 1, 4, true, true, 3><<<128, 256, 0, stream>>>(
            W1, 512, X, 512, B1, 8192, dvec, 4, 32, 512, 0);

        // 3) H1 = ADJ @ B1^T  (M=8192, N=256, K=8192), split-K=4
        agg_k<64, 256, 256, 1, 4><<<512, 256, 0, stream>>>(
            ADJH, 8192, B1, 8192, H1P, 256, 128, 2048, 2097152LL);
        reduce1_k<<<2048, 256, 0, stream>>>(H1P, dvec, X1, 4);

        // 4) B2[c][j] = bf16(d_j * (X1 @ W2^T)[j,c]), swizzled store
        gemm_k<16, 256, 1, 4, true, false, 3><<<32, 256, 0, stream>>>(
            W2, 256, X1, 256, B2, 8192, dvec, 1, 32, 256, 0);

        // 5) H2 = ADJ @ B2^T  (M=8192, N=16, K=8192), split-K=8
        agg_k<128, 32, 16, 4, 1><<<512, 256, 0, stream>>>(
            ADJH, 8192, B2, 8192, H2P, 16, 64, 1024, 131072LL);

        // 6) d_i scale + log-softmax
        final_k<<<32, 256, 0, stream>>>(H2P, dvec, out, 8);
        return;
    }

    // ---- fallback: fp32-adjacency path (R1 structure, spill-reduced gemm)
    float* dvec = (float*)(ws + 0);
    u16*   B1   = (u16*)(ws + 32768);
    u16*   X1   = (u16*)(ws + 4227072);
    u16*   B2   = (u16*)(ws + 8421376);
    float* H2P  = (float*)(ws + 8683520);
    float* H1P  = (float*)(ws + 12877824);

    int SK1, SK2; bool useH1P;
    if      (ws_size >= 46432256ULL)  { SK1 = 4; SK2 = 8; useH1P = true;  }
    else if (ws_size >= 29655040ULL)  { SK1 = 2; SK2 = 8; useH1P = true;  }
    else if (ws_size >= 12877824ULL)  { SK1 = 1; SK2 = 8; useH1P = false; }
    else                              { SK1 = 1; SK2 = 1; useH1P = false; }

    deg_k<false><<<8192, 256, 0, stream>>>(ADJ, dvec, nullptr);
    gemm_k<64, 256, 1, 4, true, true, 1><<<128, 256, 0, stream>>>(
        W1, 512, X, 512, B1, 8192, dvec, 4, 32, 512, 0);
    if (useH1P) {
        gemm_k<64, 256, 1, 4, true, false, 0><<<128 * SK1, 256, 0, stream>>>(
            ADJ, 8192, B1, 8192, H1P, 256, dvec, 128, 1, 8192 / SK1, 2097152LL);
        reduce1_k<<<2048, 256, 0, stream>>>(H1P, dvec, X1, SK1);
    } else {
        gemm_k<64, 256, 1, 4, true, false, 2><<<128, 256, 0, stream>>>(
            ADJ, 8192, B1, 8192, X1, 256, dvec, 128, 1, 8192, 0);
    }
    gemm_k<16, 256, 1, 4, true, false, 1><<<32, 256, 0, stream>>>(
        W2, 256, X1, 256, B2, 8192, dvec, 1, 32, 256, 0);
    gemm_k<128, 16, 4, 1, true, false, 0><<<64 * SK2, 256, 0, stream>>>(
        ADJ, 8192, B2, 8192, H2P, 16, dvec, 64, 1, 8192 / SK2, 131072LL);
    final_k<<<32, 256, 0, stream>>>(H2P, dvec, out, SK2);
}

// Round 3
// 197.361 us; speedup vs baseline: 2.0502x; 1.2672x over previous
//
#include <hip/hip_runtime.h>

typedef __attribute__((ext_vector_type(8))) short bf16x8;   // 8 bf16 (4 VGPRs)
typedef __attribute__((ext_vector_type(4))) float f32x4;    // MFMA acc
typedef unsigned short u16;
typedef unsigned int   u32;
typedef unsigned char  u8;

#define DEVI __device__ __forceinline__

// fp32 -> bf16 round-to-nearest-even
DEVI u16 f2bf(float f) {
    u32 u = __float_as_uint(f);
    u32 r = (u + 0x7FFFu + ((u >> 16) & 1u)) >> 16;
    return (u16)r;
}
DEVI u32 pk(float a, float b) {
    return (u32)f2bf(a) | ((u32)f2bf(b) << 16);
}
// 4x fp32 -> 4x fp8 e4m3 (OCP) packed in one dword
DEVI u32 cvt8(float a, float b, float c, float d) {
    int w = 0;
    w = __builtin_amdgcn_cvt_pk_fp8_f32(a, b, w, false);
    w = __builtin_amdgcn_cvt_pk_fp8_f32(c, d, w, true);
    return (u32)w;
}
// async global->LDS, 16B per lane (global_load_lds_dwordx4)
DEVI void gld16(const void* g, void* l) {
    __builtin_amdgcn_global_load_lds(
        (const __attribute__((address_space(1))) u32*)g,
        (__attribute__((address_space(3))) u32*)l, 16, 0, 0);
}

// ---------------------------------------------------------------------------
// Kernel 1: d[i] = rsqrt(rowsum(adj)); optionally write fp8 PRE-SWIZZLED adj.
// Swizzle: 16B chunks XOR'd within 64B groups by (row&3)  (rule #21 producer-
// side swizzle; 64B group == BK so gld16-staged tiles stay self-contained).
// ---------------------------------------------------------------------------
template<bool WRITE_H>
__global__ __launch_bounds__(256)
void deg_k(const float* __restrict__ adj, float* __restrict__ dvec,
           u8* __restrict__ adjh) {
    const int row = blockIdx.x;
    const int t   = threadIdx.x;
    const float4* p = (const float4*)(adj + (long long)row * 8192);
    float s = 0.f;
#pragma unroll
    for (int i = 0; i < 2; ++i) {
        int c = t + i * 256;                 // 16-elem chunk index in [0,512)
        float4 v0 = p[4 * c + 0];
        float4 v1 = p[4 * c + 1];
        float4 v2 = p[4 * c + 2];
        float4 v3 = p[4 * c + 3];
        s += (v0.x + v0.y) + (v0.z + v0.w) + (v1.x + v1.y) + (v1.z + v1.w) +
             (v2.x + v2.y) + (v2.z + v2.w) + (v3.x + v3.y) + (v3.z + v3.w);
        if constexpr (WRITE_H) {
            uint4 w = make_uint4(cvt8(v0.x, v0.y, v0.z, v0.w),
                                 cvt8(v1.x, v1.y, v1.z, v1.w),
                                 cvt8(v2.x, v2.y, v2.z, v2.w),
                                 cvt8(v3.x, v3.y, v3.z, v3.w));
            int cs = (c & ~3) | ((c & 3) ^ (row & 3));
            *(uint4*)(adjh + (long long)row * 8192 + (long long)cs * 16) = w;
        }
    }
#pragma unroll
    for (int off = 32; off; off >>= 1) s += __shfl_down(s, off, 64);
    __shared__ float red[4];
    if ((t & 63) == 0) red[t >> 6] = s;
    __syncthreads();
    if (t == 0) dvec[row] = 1.0f / sqrtf(red[0] + red[1] + red[2] + red[3]);
}

// ---------------------------------------------------------------------------
// Small MFMA GEMM, transposed output repack to fp8:
//   Out[n][m] = fp8( SC * dvec[m] * sum_k A[m][k]*B[n][k] ),  pre-swizzled.
//   AMODE 0: A fp32.   AMODE 2: A = relu(sum of 4 f32 split-K parts,
//            stride 2097152) * dvec[m]/64  (fused layer-1 reduce).
//   B always fp32.  bf16 MFMA.  ntiles==1 (BN = full N).
// ---------------------------------------------------------------------------
template<int BM, int BN, int WM, int WN, int AMODE, int SC>
__global__ __launch_bounds__(256)
void gemmsw_k(const void* __restrict__ Ap, int lda,
              const float* __restrict__ Bp, int ldb,
              u8* __restrict__ Op, int ldo,
              const float* __restrict__ dvec,
              int mtiles, int klen) {
    constexpr int BK  = 64;
    constexpr int WTM = BM / WM, WTN = BN / WN;
    constexpr int FM  = WTM / 16, FN = WTN / 16;
    constexpr int SA  = BM * BK;   // u16 elements
    constexpr int SB  = BN * BK;
    __shared__ __align__(16) u16 lds[SA + SB];

    const int t   = threadIdx.x;
    const int mt  = blockIdx.x % mtiles;
    const int m0  = mt * BM;

    const int lane = t & 63, lrow = lane & 15, kg = lane >> 4;
    const int wave = t >> 6;
    const int wr0  = (wave % WM) * WTM;
    const int wc0  = (wave / WM) * WTN;

    f32x4 acc[FM][FN] = {};

    auto stage = [&](int k0) {
        char* AB = (char*)lds;
        char* BB = (char*)(lds + SA);
        if constexpr (AMODE == 0) {
            constexpr int NA = BM * 16 / 256;
#pragma unroll
            for (int i = 0; i < NA; ++i) {
                int idx = t + i * 256, r = idx >> 4, c = idx & 15;
                float4 v = *(const float4*)((const float*)Ap +
                            (long long)(m0 + r) * lda + k0 + c * 4);
                int off = r * 128 + ((((c >> 1) ^ (r & 7)) << 4) | ((c & 1) << 3));
                *(uint2*)(AB + off) = make_uint2(pk(v.x, v.y), pk(v.z, v.w));
            }
        } else {   // AMODE 2: fused 4-part reduce + relu + d/64, emit bf16
            constexpr int NA = BM * 8 / 256;
#pragma unroll
            for (int i = 0; i < NA; ++i) {
                int idx = t + i * 256, r = idx >> 3, j8 = idx & 7;
                const float* base = (const float*)Ap +
                                    (long long)(m0 + r) * lda + k0 + j8 * 8;
                float4 s0 = *(const float4*)(base);
                float4 s1 = *(const float4*)(base + 4);
#pragma unroll
                for (int pp = 1; pp < 4; ++pp) {
                    float4 a0 = *(const float4*)(base + (long long)pp * 2097152);
                    float4 a1 = *(const float4*)(base + (long long)pp * 2097152 + 4);
                    s0.x += a0.x; s0.y += a0.y; s0.z += a0.z; s0.w += a0.w;
                    s1.x += a1.x; s1.y += a1.y; s1.z += a1.z; s1.w += a1.w;
                }
                float dv = dvec[m0 + r] * 0.015625f;
                uint4 w = make_uint4(
                    pk(fmaxf(s0.x, 0.f) * dv, fmaxf(s0.y, 0.f) * dv),
                    pk(fmaxf(s0.z, 0.f) * dv, fmaxf(s0.w, 0.f) * dv),
                    pk(fmaxf(s1.x, 0.f) * dv, fmaxf(s1.y, 0.f) * dv),
                    pk(fmaxf(s1.z, 0.f) * dv, fmaxf(s1.w, 0.f) * dv));
                *(uint4*)(AB + r * 128 + ((j8 ^ (r & 7)) << 4)) = w;
            }
        }
        {   // B fp32  (BN*16 is always >= 256 here: BN in {16,256})
            constexpr int NB = BN * 16 / 256;
#pragma unroll
            for (int i = 0; i < NB; ++i) {
                int idx = t + i * 256, r = idx >> 4, c = idx & 15;
                float4 v = *(const float4*)(Bp + (long long)r * ldb + k0 + c * 4);
                int off = r * 128 + ((((c >> 1) ^ (r & 7)) << 4) | ((c & 1) << 3));
                *(uint2*)(BB + off) = make_uint2(pk(v.x, v.y), pk(v.z, v.w));
            }
        }
    };

    auto compute = [&]() {
        const char* AB = (const char*)lds;
        const char* BB = (const char*)(lds + SA);
#pragma unroll
        for (int s = 0; s < 2; ++s) {
            bf16x8 a[FM]; bf16x8 b[FN];
#pragma unroll
            for (int f = 0; f < FM; ++f) {
                int r = wr0 + f * 16 + lrow;
                a[f] = *(const bf16x8*)(AB + r * 128 + (((s * 4 + kg) ^ (r & 7)) << 4));
            }
#pragma unroll
            for (int f = 0; f < FN; ++f) {
                int r = wc0 + f * 16 + lrow;
                b[f] = *(const bf16x8*)(BB + r * 128 + (((s * 4 + kg) ^ (r & 7)) << 4));
            }
#pragma unroll
            for (int i = 0; i < FM; ++i)
#pragma unroll
                for (int j = 0; j < FN; ++j)
                    acc[i][j] = __builtin_amdgcn_mfma_f32_16x16x32_bf16(
                        a[i], b[j], acc[i][j], 0, 0, 0);
        }
    };

    const int NT = klen / BK;
    for (int tt = 0; tt < NT; ++tt) {
        stage(tt * BK);
        __syncthreads();
        compute();
        __syncthreads();
    }

    // ---- transposed fp8 repack epilogue (LDS bounce), pre-swizzled store
    __syncthreads();
    float* LF = (float*)lds;
    constexpr int LDSBYTES = (SA + SB) * 2;
    constexpr int PHR = (BM * BN * 4 <= LDSBYTES) ? BM : (BM / 2);
    static_assert(PHR * BN * 4 <= LDSBYTES, "repack phase too big");
    constexpr int NPH = BM / PHR;
    constexpr int MG  = PHR / 16;
#pragma unroll
    for (int ph = 0; ph < NPH; ++ph) {
        if (ph) __syncthreads();
#pragma unroll
        for (int i = 0; i < FM; ++i) {
            int mlb = wr0 + i * 16 + kg * 4;
            if (mlb >= ph * PHR && mlb < (ph + 1) * PHR) {
#pragma unroll
                for (int rr = 0; rr < 4; ++rr) {
                    float dv = dvec[m0 + mlb + rr] * (float)SC;
#pragma unroll
                    for (int j = 0; j < FN; ++j)
                        LF[(mlb - ph * PHR + rr) * BN + wc0 + j * 16 + lrow] =
                            acc[i][j][rr] * dv;
                }
            }
        }
        __syncthreads();
        constexpr int CHK = BN * MG;
#pragma unroll
        for (int it = 0; it < (CHK + 255) / 256; ++it) {
            int q = t + it * 256;
            if (q < CHK) {
                int n = q / MG, mg = q % MG;
                float f[16];
#pragma unroll
                for (int e = 0; e < 16; ++e) f[e] = LF[(mg * 16 + e) * BN + n];
                uint4 w = make_uint4(cvt8(f[0], f[1], f[2], f[3]),
                                     cvt8(f[4], f[5], f[6], f[7]),
                                     cvt8(f[8], f[9], f[10], f[11]),
                                     cvt8(f[12], f[13], f[14], f[15]));
                int gj = (m0 >> 4) + ph * MG + mg;
                int cs = (gj & ~3) | ((gj & 3) ^ (n & 3));
                *(uint4*)(Op + (long long)n * ldo + (long long)cs * 16) = w;
            }
        }
    }
}

// ---------------------------------------------------------------------------
// Layer-1 aggregate, fp8: H1P[kp][i][h] = sum_k ADJH[i][k]*B1[h][k]
// BM=64, BN=256, 4 waves (WN=4). global_load_lds dbuf, counted vmcnt(5).
// Inputs pre-swizzled (16B chunks ^ (row&3) within 64B groups).
// ---------------------------------------------------------------------------
__global__ __launch_bounds__(256)
void agg1f8_k(const u8* __restrict__ A, const u8* __restrict__ B,
              float* __restrict__ Op, int mtiles, int klen, long long kstride) {
    constexpr int BM = 64, BK = 64;
    constexpr int ABUF = BM * BK;          // 4096 B
    constexpr int BBUF = 256 * BK;         // 16384 B
    constexpr int BUF  = ABUF + BBUF;      // 20480 B
    __shared__ __align__(16) u8 lds[2 * BUF];

    const int t  = threadIdx.x;
    const int mt = blockIdx.x % mtiles;
    const int kp = blockIdx.x / mtiles;
    const int m0 = mt * BM;
    const long long k00 = (long long)kp * klen;
    const int lane = t & 63, lrow = lane & 15, kg = lane >> 4;
    const int wc0  = (t >> 6) * 64;

    f32x4 acc[4][4] = {};

    auto stage = [&](long long k0, int pb) {
        u8* dst = lds + pb * BUF;
#pragma unroll
        for (int i = 0; i < 5; ++i) {
            int c = t + i * 256;
            const u8* src;
            if (i == 0)
                src = A + (long long)(m0 + (c >> 2)) * 8192 + k0 + (c & 3) * 16;
            else {
                int cb = c - 256;
                src = B + (long long)(cb >> 2) * 8192 + k0 + (cb & 3) * 16;
            }
            gld16(src, dst + c * 16);
        }
    };

    auto compute = [&](int pb) {
        const u8* Ab = lds + pb * BUF;
        const u8* Bb = Ab + ABUF;
#pragma unroll
        for (int s = 0; s < 2; ++s) {
            const int sc = s * 4 + kg;
            long long a[4], b[4];
#pragma unroll
            for (int f = 0; f < 4; ++f) {
                int r = f * 16 + lrow;
                a[f] = *(const long long*)(Ab + r * 64 +
                        (((sc >> 1) ^ (r & 3)) << 4) + ((sc & 1) << 3));
            }
#pragma unroll
            for (int f = 0; f < 4; ++f) {
                int r = wc0 + f * 16 + lrow;
                b[f] = *(const long long*)(Bb + r * 64 +
                        (((sc >> 1) ^ (r & 3)) << 4) + ((sc & 1) << 3));
            }
#pragma unroll
            for (int i = 0; i < 4; ++i)
#pragma unroll
                for (int j = 0; j < 4; ++j)
                    acc[i][j] = __builtin_amdgcn_mfma_f32_16x16x32_fp8_fp8(
                        a[i], b[j], acc[i][j], 0, 0, 0);
        }
    };

    stage(k00, 0);
    const int NT = klen / BK;
    for (int tt = 0; tt < NT; ++tt) {
        const int p = tt & 1;
        if (tt + 1 < NT) {
            stage(k00 + (long long)(tt + 1) * BK, p ^ 1);
            asm volatile("s_waitcnt vmcnt(5)" ::: "memory");  // next tile in flight
        } else {
            asm volatile("s_waitcnt vmcnt(0)" ::: "memory");
        }
        __builtin_amdgcn_s_barrier();
        compute(p);
        asm volatile("" ::: "memory");
        __builtin_amdgcn_s_barrier();
    }

#pragma unroll
    for (int i = 0; i < 4; ++i)
#pragma unroll
        for (int j = 0; j < 4; ++j)
#pragma unroll
            for (int rr = 0; rr < 4; ++rr) {
                int m = m0 + i * 16 + kg * 4 + rr;
                int n = wc0 + j * 16 + lrow;
                Op[kp * kstride + (long long)m * 256 + n] = acc[i][j][rr];
            }
}

// ---------------------------------------------------------------------------
// Layer-2 aggregate, fp8: H2P[kp][i][c] = sum_k ADJH[i][k]*B2[c][k]
// BM=64, 16 output cols, 4 waves (WM=4). B-slice (16 x 2048B) prestaged whole;
// K-loop streams A only (NLD=1, vmcnt(1)). klen fixed 2048 (split-K=4).
// ---------------------------------------------------------------------------
__global__ __launch_bounds__(256)
void agg2f8_k(const u8* __restrict__ A, const u8* __restrict__ B,
              float* __restrict__ Op, int mtiles) {
    constexpr int BM = 64, BK = 64, KLEN = 2048;
    constexpr int ABUF = BM * BK;                     // 4096 B
    __shared__ __align__(16) u8 lds[2 * ABUF + 16 * KLEN];  // 40960 B

    const int t  = threadIdx.x;
    const int mt = blockIdx.x % mtiles;
    const int kp = blockIdx.x / mtiles;
    const int m0 = mt * BM;
    const long long k00 = (long long)kp * KLEN;
    const int lane = t & 63, lrow = lane & 15, kg = lane >> 4;
    const int wr0  = (t >> 6) * 16;
    u8* Bl = lds + 2 * ABUF;

    // prestage whole B K-slice: 16 rows x 2048 B
#pragma unroll
    for (int i = 0; i < 8; ++i) {
        int q = t + i * 256;
        gld16(B + (long long)(q >> 7) * 8192 + k00 + (q & 127) * 16,
              Bl + q * 16);
    }

    auto stageA = [&](long long k0, int pb) {
        int c = t;   // 256 chunks exactly
        gld16(A + (long long)(m0 + (c >> 2)) * 8192 + k0 + (c & 3) * 16,
              lds + pb * ABUF + c * 16);
    };

    f32x4 acc = {};
    stageA(k00, 0);
    const int NT = KLEN / BK;
    for (int tt = 0; tt < NT; ++tt) {
        const int p = tt & 1;
        if (tt + 1 < NT) {
            stageA(k00 + (long long)(tt + 1) * BK, p ^ 1);
            asm volatile("s_waitcnt vmcnt(1)" ::: "memory");
        } else {
            asm volatile("s_waitcnt vmcnt(0)" ::: "memory");
        }
        __builtin_amdgcn_s_barrier();
        const u8* Ab = lds + p * ABUF;
#pragma unroll
        for (int s = 0; s < 2; ++s) {
            const int sc = s * 4 + kg;
            int ra = wr0 + lrow;
            long long a = *(const long long*)(Ab + ra * 64 +
                           (((sc >> 1) ^ (ra & 3)) << 4) + ((sc & 1) << 3));
            int rb = lrow;
            long long b = *(const long long*)(Bl + rb * KLEN + tt * 64 +
                           (((sc >> 1) ^ (rb & 3)) << 4) + ((sc & 1) << 3));
            acc = __builtin_amdgcn_mfma_f32_16x16x32_fp8_fp8(a, b, acc, 0, 0, 0);
        }
        asm volatile("" ::: "memory");
        __builtin_amdgcn_s_barrier();
    }

#pragma unroll
    for (int rr = 0; rr < 4; ++rr) {
        int m = m0 + wr0 + kg * 4 + rr;
        Op[(long long)kp * 131072 + (long long)m * 16 + lrow] = acc[rr];
    }
}

// ---------------------------------------------------------------------------
// out[i][c] = log_softmax(scl * d[i] * sum_p H2p[p][i][c])
// ---------------------------------------------------------------------------
__global__ __launch_bounds__(256)
void final_k(const float* __restrict__ H, const float* __restrict__ dvec,
             float* __restrict__ out, int parts, float scl) {
    int i = blockIdx.x * 256 + threadIdx.x;
    float z[16];
#pragma unroll
    for (int c = 0; c < 16; c += 4) {
        float4 v = *(const float4*)(H + (long long)i * 16 + c);
        z[c] = v.x; z[c + 1] = v.y; z[c + 2] = v.z; z[c + 3] = v.w;
    }
    for (int p = 1; p < parts; ++p) {
#pragma unroll
        for (int c = 0; c < 16; c += 4) {
            float4 v = *(const float4*)(H + (long long)p * 131072 +
                                        (long long)i * 16 + c);
            z[c] += v.x; z[c + 1] += v.y; z[c + 2] += v.z; z[c + 3] += v.w;
        }
    }
    float dv = dvec[i] * scl;
    float m = -1e30f;
#pragma unroll
    for (int c = 0; c < 16; ++c) { z[c] *= dv; m = fmaxf(m, z[c]); }
    float l = 0.f;
#pragma unroll
    for (int c = 0; c < 16; ++c) l += __expf(z[c] - m);
    float lse = m + __logf(l);
#pragma unroll
    for (int c = 0; c < 16; c += 4) {
        float4 v;
        v.x = z[c] - lse; v.y = z[c + 1] - lse;
        v.z = z[c + 2] - lse; v.w = z[c + 3] - lse;
        *(float4*)(out + (long long)i * 16 + c) = v;
    }
}

// ===========================================================================
// Fallback path (small workspace): R2's bf16 kernels, kept verbatim.
// ===========================================================================
template<int BM, int BN, int WM, int WN, bool AF32, bool BF32, int EPI>
__global__ __launch_bounds__(256)
void gemm_old_k(const void* __restrict__ Ap, int lda,
                const void* __restrict__ Bp, int ldb,
                void* __restrict__ Op, int ldo,
                const float* __restrict__ dvec,
                int mtiles, int ntiles, int klen, long long kstride) {
    constexpr int BK  = 64;
    constexpr int WTM = BM / WM, WTN = BN / WN;
    constexpr int FM  = WTM / 16, FN = WTN / 16;
    constexpr int SA  = BM * BK;
    constexpr int SB  = BN * BK;
    __shared__ __align__(16) u16 lds[SA + SB];

    const int t   = threadIdx.x;
    const int bid = blockIdx.x;
    const int mt  = bid % mtiles;
    const int nt  = (bid / mtiles) % ntiles;
    const int kp  = bid / (mtiles * ntiles);
    const int m0  = mt * BM, n0 = nt * BN;
    const long long k00 = (long long)kp * klen;

    const float* Af = (const float*)Ap;
    const u16*   Ah = (const u16*)Ap;
    const float* Bf = (const float*)Bp;
    const u16*   Bh = (const u16*)Bp;

    f32x4 acc[FM][FN] = {};

    const int lane = t & 63;
    const int lrow = lane & 15, kg = lane >> 4;
    const int wave = t >> 6;
    const int wr0  = (wave % WM) * WTM;
    const int wc0  = (wave / WM) * WTN;

    auto stage = [&](long long k0) {
        char* AB = (char*)lds;
        char* BB = (char*)(lds + SA);
        if constexpr (AF32) {
            constexpr int NA = BM * 16 / 256;
#pragma unroll
            for (int i = 0; i < NA; ++i) {
                int idx = t + i * 256, r = idx >> 4, c = idx & 15;
                float4 v = *(const float4*)(Af + (long long)(m0 + r) * lda + k0 + c * 4);
                int off = r * 128 + ((((c >> 1) ^ (r & 7)) << 4) | ((c & 1) << 3));
                *(uint2*)(AB + off) = make_uint2(pk(v.x, v.y), pk(v.z, v.w));
            }
        } else {
            constexpr int NA = (BM * 8 + 255) / 256;
#pragma unroll
            for (int i = 0; i < NA; ++i) {
                int idx = t + i * 256;
                if (BM * 8 >= 256 || idx < BM * 8) {
                    int r = idx >> 3, j = idx & 7;
                    uint4 v = *(const uint4*)(Ah + (long long)(m0 + r) * lda + k0 + j * 8);
                    *(uint4*)(AB + r * 128 + ((j ^ (r & 7)) << 4)) = v;
                }
            }
        }
        if constexpr (BF32) {
            constexpr int NB = BN * 16 / 256;
#pragma unroll
            for (int i = 0; i < NB; ++i) {
                int idx = t + i * 256, r = idx >> 4, c = idx & 15;
                float4 v = *(const float4*)(Bf + (long long)(n0 + r) * ldb + k0 + c * 4);
                int off = r * 128 + ((((c >> 1) ^ (r & 7)) << 4) | ((c & 1) << 3));
                *(uint2*)(BB + off) = make_uint2(pk(v.x, v.y), pk(v.z, v.w));
            }
        } else {
            constexpr int NB = (BN * 8 + 255) / 256;
#pragma unroll
            for (int i = 0; i < NB; ++i) {
                int idx = t + i * 256;
                if (BN * 8 >= 256 || idx < BN * 8) {
                    int r = idx >> 3, j = idx & 7;
                    uint4 v = *(const uint4*)(Bh + (long long)(n0 + r) * ldb + k0 + j * 8);
                    *(uint4*)(BB + r * 128 + ((j ^ (r & 7)) << 4)) = v;
                }
            }
        }
    };

    auto compute = [&]() {
        const char* AB = (const char*)lds;
        const char* BB = (const char*)(lds + SA);
#pragma unroll
        for (int s = 0; s < 2; ++s) {
            bf16x8 a[FM]; bf16x8 b[FN];
#pragma unroll
            for (int f = 0; f < FM; ++f) {
                int r = wr0 + f * 16 + lrow;
                a[f] = *(const bf16x8*)(AB + r * 128 + (((s * 4 + kg) ^ (r & 7)) << 4));
            }
#pragma unroll
            for (int f = 0; f < FN; ++f) {
                int r = wc0 + f * 16 + lrow;
                b[f] = *(const bf16x8*)(BB + r * 128 + (((s * 4 + kg) ^ (r & 7)) << 4));
            }
#pragma unroll
            for (int i = 0; i < FM; ++i)
#pragma unroll
                for (int j = 0; j < FN; ++j)
                    acc[i][j] = __builtin_amdgcn_mfma_f32_16x16x32_bf16(
                        a[i], b[j], acc[i][j], 0, 0, 0);
        }
    };

    const int NT = klen / BK;
    for (int tt = 0; tt < NT; ++tt) {
        stage(k00 + (long long)tt * BK);
        __syncthreads();
        compute();
        __syncthreads();
    }

#pragma unroll
    for (int i = 0; i < FM; ++i)
#pragma unroll
        for (int j = 0; j < FN; ++j)
#pragma unroll
            for (int r = 0; r < 4; ++r) {
                int m = m0 + wr0 + i * 16 + kg * 4 + r;
                int n = n0 + wc0 + j * 16 + lrow;
                float v = acc[i][j][r];
                if constexpr (EPI == 0) {
                    ((float*)Op)[kp * kstride + (long long)m * ldo + n] = v;
                } else if constexpr (EPI == 1) {
                    ((u16*)Op)[(long long)m * ldo + n] = f2bf(v * dvec[n]);
                } else {
                    ((u16*)Op)[(long long)m * ldo + n] =
                        f2bf(fmaxf(v * dvec[m], 0.0f));
                }
            }
}

__global__ __launch_bounds__(256)
void reduce1_k(const float* __restrict__ H, const float* __restrict__ dvec,
               u16* __restrict__ x1, int parts) {
    long long i = ((long long)blockIdx.x * 256 + threadIdx.x) * 4;
    float4 s = *(const float4*)(H + i);
    for (int p = 1; p < parts; ++p) {
        float4 v = *(const float4*)(H + (long long)p * 2097152 + i);
        s.x += v.x; s.y += v.y; s.z += v.z; s.w += v.w;
    }
    float dv = dvec[i >> 8];
    *(uint2*)(x1 + i) = make_uint2(
        pk(fmaxf(s.x * dv, 0.f), fmaxf(s.y * dv, 0.f)),
        pk(fmaxf(s.z * dv, 0.f), fmaxf(s.w * dv, 0.f)));
}

// ---------------------------------------------------------------------------
extern "C" void kernel_launch(void* const* d_in, const int* in_sizes, int n_in,
                              void* d_out, int out_size, void* d_ws, size_t ws_size,
                              hipStream_t stream) {
    (void)in_sizes; (void)n_in; (void)out_size;
    const float* X   = (const float*)d_in[0];   // [8192,512]
    const float* ADJ = (const float*)d_in[1];   // [8192,8192]
    const float* W1  = (const float*)d_in[2];   // [256,512]
    const float* W2  = (const float*)d_in[3];   // [16,256]
    float* out = (float*)d_out;
    char*  ws  = (char*)d_ws;

    if (ws_size >= 101021696ULL) {
        // ---- fast path: fp8 pre-swizzled adjacency + fp8 MFMA aggregates
        float* dvec = (float*)(ws + 0);           //  32 KB
        u8*    B1   = (u8*)(ws + 32768);          //   2 MB [256 h][8192 j]
        u8*    B2   = (u8*)(ws + 2129920);        // 128 KB [16 c][8192 j]
        float* H1P  = (float*)(ws + 2260992);     //  32 MB [4][8192][256]
        float* H2P  = (float*)(ws + 35815424);    //   2 MB [4][8192][16]
        u8*    ADJH = (u8*)(ws + 37912576);       //  64 MB [8192][8192] swz

        // 1) degrees + fp8 swizzled adjacency
        deg_k<true><<<8192, 256, 0, stream>>>(ADJ, dvec, ADJH);

        // 2) B1[h][j] = fp8(64 * d_j * (X @ W1^T)[j,h])   A=X, B=W1
        gemmsw_k<64, 256, 1, 4, 0, 64><<<128, 256, 0, stream>>>(
            X, 512, W1, 512, B1, 8192, dvec, 128, 512);

        // 3) H1P = ADJH @ B1^T  (split-K=4)
        agg1f8_k<<<512, 256, 0, stream>>>(ADJH, B1, H1P, 128, 2048, 2097152LL);

        // 4) B2[c][j] = fp8(8192 * d_j * (X1 @ W2^T)[j,c]),
        //    X1 = relu(d_j/64 * sum_p H1P) fused into A-staging
        gemmsw_k<64, 16, 4, 1, 2, 8192><<<128, 256, 0, stream>>>(
            H1P, 256, W2, 256, B2, 8192, dvec, 128, 256);

        // 5) H2P = ADJH @ B2^T  (split-K=4)
        agg2f8_k<<<512, 256, 0, stream>>>(ADJH, B2, H2P, 128);

        // 6) d_i/8192 scale + log-softmax
        final_k<<<32, 256, 0, stream>>>(H2P, dvec, out, 4, 1.0f / 8192.0f);
        return;
    }

    // ---- fallback: fp32-adjacency bf16 path (R2 structure)
    float* dvec = (float*)(ws + 0);
    u16*   B1   = (u16*)(ws + 32768);
    u16*   X1   = (u16*)(ws + 4227072);
    u16*   B2   = (u16*)(ws + 8421376);
    float* H2P  = (float*)(ws + 8683520);
    float* H1P  = (float*)(ws + 12877824);

    int SK1, SK2; bool useH1P;
    if      (ws_size >= 46432256ULL)  { SK1 = 4; SK2 = 8; useH1P = true;  }
    else if (ws_size >= 29655040ULL)  { SK1 = 2; SK2 = 8; useH1P = true;  }
    else if (ws_size >= 12877824ULL)  { SK1 = 1; SK2 = 8; useH1P = false; }
    else                              { SK1 = 1; SK2 = 1; useH1P = false; }

    deg_k<false><<<8192, 256, 0, stream>>>(ADJ, dvec, nullptr);
    gemm_old_k<64, 256, 1, 4, true, true, 1><<<128, 256, 0, stream>>>(
        W1, 512, X, 512, B1, 8192, dvec, 4, 32, 512, 0);
    if (useH1P) {
        gemm_old_k<64, 256, 1, 4, true, false, 0><<<128 * SK1, 256, 0, stream>>>(
            ADJ, 8192, B1, 8192, H1P, 256, dvec, 128, 1, 8192 / SK1, 2097152LL);
        reduce1_k<<<2048, 256, 0, stream>>>(H1P, dvec, X1, SK1);
    } else {
        gemm_old_k<64, 256, 1, 4, true, false, 2><<<128, 256, 0, stream>>>(
            ADJ, 8192, B1, 8192, X1, 256, dvec, 128, 1, 8192, 0);
    }
    gemm_old_k<16, 256, 1, 4, true, false, 1><<<32, 256, 0, stream>>>(
        W2, 256, X1, 256, B2, 8192, dvec, 1, 32, 256, 0);
    gemm_old_k<128, 16, 4, 1, true, false, 0><<<64 * SK2, 256, 0, stream>>>(
        ADJ, 8192, B2, 8192, H2P, 16, dvec, 64, 1, 8192 / SK2, 131072LL);
    final_k<<<32, 256, 0, stream>>>(H2P, dvec, out, SK2, 1.0f);
}